// Round 4
// baseline (149.828 us; speedup 1.0000x reference)
//
#include <hip/hip_runtime.h>

#define NA 2048
#define NT 256

__device__ __forceinline__ float silu_f(float x) { return x / (1.0f + __expf(-x)); }

__device__ __forceinline__ float wave_reduce(float v) {
    #pragma unroll
    for (int off = 32; off > 0; off >>= 1) v += __shfl_down(v, off, 64);
    return v;
}

// ---------------------------------------------------------------------------
// k1: RBF features + both MLPs for atom i = blockIdx.x.
// Features accumulate via ds_add_f32 into sfeat[16] (cutoff branch is ~1-2
// lanes/wave -> atomic traffic is tiny; kills 96 shuffles + 16 VGPRs).
// Also zero-inits the k2 completion counter (block 0).
// ---------------------------------------------------------------------------
__global__ __launch_bounds__(NT) void k1_feat_mlp(
    const float* __restrict__ pos,
    const float* __restrict__ cw1, const float* __restrict__ cb1,
    const float* __restrict__ cw2, const float* __restrict__ cb2,
    const float* __restrict__ cw3, const float* __restrict__ cb3,
    const float* __restrict__ ew1, const float* __restrict__ eb1,
    const float* __restrict__ ew2, const float* __restrict__ eb2,
    const float* __restrict__ ew3, const float* __restrict__ eb3,
    float4* __restrict__ pxyzq, float* __restrict__ rawq, float* __restrict__ esr,
    int* __restrict__ counter)
{
    __shared__ float sfeat[16];
    __shared__ float sh1[4][64];
    const int i = blockIdx.x;
    const int tid = threadIdx.x, lane = tid & 63, wv = tid >> 6;
    const float pix = pos[3*i], piy = pos[3*i+1], piz = pos[3*i+2];

    if (tid < 16) sfeat[tid] = 0.0f;
    if (i == 0 && tid == 0) *counter = 0;     // reset for k2's last-block gate
    __syncthreads();

    for (int j = tid; j < NA; j += NT) {
        float dx = pix - pos[3*j], dy = piy - pos[3*j+1], dz = piz - pos[3*j+2];
        float d2 = dx*dx + dy*dy + dz*dz;
        if (d2 > 0.0f && d2 < 25.0f) {
            float d  = sqrtf(d2);
            float sm = 0.5f * (1.0f + __cosf(0.6283185307179586f * d)); // cos(pi*d/5)
            #pragma unroll
            for (int r = 0; r < 16; ++r) {
                float t = d - (0.5f + 0.3f * (float)r);   // centers linspace(0.5,5,16)
                atomicAdd(&sfeat[r], sm * __expf(-t * t * 25.28395061728395f)); // 1/(2 eta^2)
            }
        }
    }
    __syncthreads();

    // Both MLPs: waves 0,1 are the real tasks; waves 2,3 duplicate so the
    // barrier between layer-1 write and layer-2 read is non-divergent.
    const int which = wv & 1;   // 0: charge MLP, 1: energy MLP
    const float* w1 = which ? ew1 : cw1;
    const float* b1 = which ? eb1 : cb1;
    const float* w2 = which ? ew2 : cw2;
    const float* b2 = which ? eb2 : cb2;
    const float* w3 = which ? ew3 : cw3;
    const float* b3 = which ? eb3 : cb3;

    float s = b1[lane];
    #pragma unroll
    for (int r = 0; r < 16; ++r) s += sfeat[r] * w1[r * 64 + lane];
    sh1[wv][lane] = silu_f(s);
    __syncthreads();

    float s2 = b2[lane];
    #pragma unroll 8
    for (int k = 0; k < 64; ++k) s2 += sh1[wv][k] * w2[k * 64 + lane];
    float p = silu_f(s2) * w3[lane];
    p = wave_reduce(p);

    if (lane == 0 && wv < 2) {
        float o = p + b3[0];
        if (wv == 0) { rawq[i] = o; pxyzq[i] = make_float4(pix, piy, piz, o); }
        else         { esr[i] = o; }
    }
}

// ---------------------------------------------------------------------------
// k2: pair pass with RAW charges + last-block finalize.
//   s_i = sum' qr_j/r_ij, t_i = sum' 1/r_ij
//   E_lr = 0.5*(S_qq + c*(S_qt + S_s) + c^2*S_t), c = -sum(qr)/N
// Last block to finish reduces the 2048-wide arrays, writes out[0] and the
// corrected charges out[1..2048].
// ---------------------------------------------------------------------------
__global__ __launch_bounds__(NT) void k2_pair_final(
    const float4* __restrict__ pxyzq,
    const float* __restrict__ rawq, const float* __restrict__ esr,
    float* __restrict__ sarr, float* __restrict__ tarr,
    int* __restrict__ counter, float* __restrict__ out)
{
    __shared__ float ws[4][2];
    __shared__ float wred[4][6];
    __shared__ int   is_last;
    __shared__ float sc;
    const int i = blockIdx.x, tid = threadIdx.x, lane = tid & 63, wv = tid >> 6;
    const float4 pi = pxyzq[i];
    float s = 0.0f, t = 0.0f;
    for (int j = tid; j < NA; j += NT) {
        float4 pj = pxyzq[j];
        float dx = pi.x - pj.x, dy = pi.y - pj.y, dz = pi.z - pj.z;
        float d2 = dx*dx + dy*dy + dz*dz;
        float rinv = rsqrtf(d2);
        if (j == i) rinv = 0.0f;
        t += rinv;
        s += pj.w * rinv;
    }
    s = wave_reduce(s);
    t = wave_reduce(t);
    if (lane == 0) { ws[wv][0] = s; ws[wv][1] = t; }
    __syncthreads();
    if (tid == 0) {
        sarr[i] = ws[0][0] + ws[1][0] + ws[2][0] + ws[3][0];
        tarr[i] = ws[0][1] + ws[1][1] + ws[2][1] + ws[3][1];
        __threadfence();                        // publish sarr/tarr
        int old = atomicAdd(counter, 1);
        is_last = (old == NA - 1) ? 1 : 0;
    }
    __syncthreads();
    if (!is_last) return;

    // ---- finalize (exactly one block reaches here) ----
    __threadfence();                            // acquire all blocks' sarr/tarr
    float pq = 0, pe = 0, pqq = 0, pqt = 0, ps = 0, pt = 0;
    for (int idx = tid; idx < NA; idx += NT) {
        float q = rawq[idx], sv = sarr[idx], tv = tarr[idx];
        pq += q; pe += esr[idx]; pqq += q * sv; pqt += q * tv; ps += sv; pt += tv;
    }
    pq  = wave_reduce(pq);  pe = wave_reduce(pe);  pqq = wave_reduce(pqq);
    pqt = wave_reduce(pqt); ps = wave_reduce(ps);  pt  = wave_reduce(pt);
    if (lane == 0) {
        wred[wv][0] = pq; wred[wv][1] = pe; wred[wv][2] = pqq;
        wred[wv][3] = pqt; wred[wv][4] = ps; wred[wv][5] = pt;
    }
    __syncthreads();
    if (tid == 0) {
        float q  = wred[0][0] + wred[1][0] + wred[2][0] + wred[3][0];
        float e  = wred[0][1] + wred[1][1] + wred[2][1] + wred[3][1];
        float qq = wred[0][2] + wred[1][2] + wred[2][2] + wred[3][2];
        float qt = wred[0][3] + wred[1][3] + wred[2][3] + wred[3][3];
        float ss = wred[0][4] + wred[1][4] + wred[2][4] + wred[3][4];
        float tt = wred[0][5] + wred[1][5] + wred[2][5] + wred[3][5];
        float c = -q * (1.0f / (float)NA);
        sc = c;
        out[0] = 0.5f * (qq + c * (qt + ss) + c * c * tt) + e;
    }
    __syncthreads();
    const float c = sc;
    for (int idx = tid; idx < NA; idx += NT) out[1 + idx] = rawq[idx] + c;
}

extern "C" void kernel_launch(void* const* d_in, const int* in_sizes, int n_in,
                              void* d_out, int out_size, void* d_ws, size_t ws_size,
                              hipStream_t stream) {
    const float* pos = (const float*)d_in[0];
    const float* cw1 = (const float*)d_in[1];
    const float* cb1 = (const float*)d_in[2];
    const float* cw2 = (const float*)d_in[3];
    const float* cb2 = (const float*)d_in[4];
    const float* cw3 = (const float*)d_in[5];
    const float* cb3 = (const float*)d_in[6];
    const float* ew1 = (const float*)d_in[7];
    const float* eb1 = (const float*)d_in[8];
    const float* ew2 = (const float*)d_in[9];
    const float* eb2 = (const float*)d_in[10];
    const float* ew3 = (const float*)d_in[11];
    const float* eb3 = (const float*)d_in[12];
    float* out = (float*)d_out;

    float4* pxyzq   = (float4*)d_ws;              // 2048 float4
    float*  rawq    = (float*)(pxyzq + NA);       // 2048
    float*  esr     = rawq + NA;                  // 2048
    float*  sarr    = esr + NA;                   // 2048
    float*  tarr    = sarr + NA;                  // 2048
    int*    counter = (int*)(tarr + NA);          // 1

    k1_feat_mlp<<<NA, NT, 0, stream>>>(pos,
                                       cw1, cb1, cw2, cb2, cw3, cb3,
                                       ew1, eb1, ew2, eb2, ew3, eb3,
                                       pxyzq, rawq, esr, counter);
    k2_pair_final<<<NA, NT, 0, stream>>>(pxyzq, rawq, esr, sarr, tarr, counter, out);
}

// Round 5
// 107.134 us; speedup vs baseline: 1.3985x; 1.3985x over previous
//
#include <hip/hip_runtime.h>

#define NA 2048
#define NT 256

__device__ __forceinline__ float silu_f(float x) { return x / (1.0f + __expf(-x)); }

__device__ __forceinline__ float wave_reduce(float v) {
    #pragma unroll
    for (int off = 32; off > 0; off >>= 1) v += __shfl_down(v, off, 64);
    return v;
}

// ---------------------------------------------------------------------------
// k1: RBF features + both MLPs, ONE WAVE PER ATOM, barrier-free.
// 512 blocks x 256 threads; wave wv of block b owns atom i = b*4 + wv.
// Features: register accs + shuffle reduce + shuffle broadcast.
// MLP layer 2: hidden vector exchanged via __shfl broadcast (no LDS).
// ---------------------------------------------------------------------------
__global__ __launch_bounds__(NT) void k1_feat_mlp(
    const float* __restrict__ pos,
    const float* __restrict__ cw1, const float* __restrict__ cb1,
    const float* __restrict__ cw2, const float* __restrict__ cb2,
    const float* __restrict__ cw3, const float* __restrict__ cb3,
    const float* __restrict__ ew1, const float* __restrict__ eb1,
    const float* __restrict__ ew2, const float* __restrict__ eb2,
    const float* __restrict__ ew3, const float* __restrict__ eb3,
    float4* __restrict__ pxyzq, float* __restrict__ rawq, float* __restrict__ esr)
{
    const int tid = threadIdx.x, lane = tid & 63, wv = tid >> 6;
    const int i = blockIdx.x * 4 + wv;
    const float pix = pos[3*i], piy = pos[3*i+1], piz = pos[3*i+2];

    float acc[16];
    #pragma unroll
    for (int r = 0; r < 16; ++r) acc[r] = 0.0f;

    for (int j = lane; j < NA; j += 64) {
        float dx = pix - pos[3*j], dy = piy - pos[3*j+1], dz = piz - pos[3*j+2];
        float d2 = dx*dx + dy*dy + dz*dz;
        if (d2 > 0.0f && d2 < 25.0f) {
            float d  = sqrtf(d2);
            float sm = 0.5f * (1.0f + __cosf(0.6283185307179586f * d)); // cos(pi*d/5)
            #pragma unroll
            for (int r = 0; r < 16; ++r) {
                float t = d - (0.5f + 0.3f * (float)r);   // centers linspace(0.5,5,16)
                acc[r] += sm * __expf(-t * t * 25.28395061728395f); // 1/(2 eta^2)
            }
        }
    }

    // reduce to lane 0 then broadcast: every lane gets the full feature vector
    float feat[16];
    #pragma unroll
    for (int r = 0; r < 16; ++r) {
        float v = wave_reduce(acc[r]);
        feat[r] = __shfl(v, 0, 64);
    }

    // both MLPs sequentially; lane = hidden unit index
    float oq = 0.0f, oe = 0.0f;
    #pragma unroll
    for (int which = 0; which < 2; ++which) {
        const float* w1 = which ? ew1 : cw1;
        const float* b1 = which ? eb1 : cb1;
        const float* w2 = which ? ew2 : cw2;
        const float* b2 = which ? eb2 : cb2;
        const float* w3 = which ? ew3 : cw3;

        float s = b1[lane];
        #pragma unroll
        for (int r = 0; r < 16; ++r) s += feat[r] * w1[r * 64 + lane];
        float h1 = silu_f(s);

        float s2 = b2[lane];
        #pragma unroll 8
        for (int k = 0; k < 64; ++k)
            s2 += __shfl(h1, k, 64) * w2[k * 64 + lane];

        float p = silu_f(s2) * w3[lane];
        p = wave_reduce(p);              // valid on lane 0
        if (which == 0) oq = p; else oe = p;
    }

    if (lane == 0) {
        float q = oq + cb3[0];
        rawq[i] = q;
        pxyzq[i] = make_float4(pix, piy, piz, q);
        esr[i] = oe + eb3[0];
    }
}

// ---------------------------------------------------------------------------
// k2: pair pass with RAW charges. s_i = sum' qr_j/r_ij, t_i = sum' 1/r_ij.
// One block per atom, coalesced float4 loads (L2-resident), no LDS staging.
// (byte-identical to round 3 — proven fast; round 4's in-kernel handoff
//  regressed 45 us from per-block device-scope fences)
// ---------------------------------------------------------------------------
__global__ __launch_bounds__(NT) void k2_pair(const float4* __restrict__ pxyzq,
                                              float* __restrict__ sarr,
                                              float* __restrict__ tarr)
{
    __shared__ float ws[4][2];
    const int i = blockIdx.x, tid = threadIdx.x, lane = tid & 63, wv = tid >> 6;
    const float4 pi = pxyzq[i];
    float s = 0.0f, t = 0.0f;
    for (int j = tid; j < NA; j += NT) {
        float4 pj = pxyzq[j];
        float dx = pi.x - pj.x, dy = pi.y - pj.y, dz = pi.z - pj.z;
        float d2 = dx*dx + dy*dy + dz*dz;
        if (j != i) {
            float rinv = rsqrtf(d2);
            t += rinv;
            s += pj.w * rinv;
        }
    }
    s = wave_reduce(s);
    t = wave_reduce(t);
    if (lane == 0) { ws[wv][0] = s; ws[wv][1] = t; }
    __syncthreads();
    if (tid == 0) {
        sarr[i] = ws[0][0] + ws[1][0] + ws[2][0] + ws[3][0];
        tarr[i] = ws[0][1] + ws[1][1] + ws[2][1] + ws[3][1];
    }
}

// ---------------------------------------------------------------------------
// k3: final reduction + correction + outputs.
// E_lr = 0.5*(S_qq + c*(S_qt + S_s) + c^2*S_t), c = -sum(qr)/N
// ---------------------------------------------------------------------------
__global__ __launch_bounds__(NT) void k3_final(const float* __restrict__ rawq,
                                               const float* __restrict__ esr,
                                               const float* __restrict__ sarr,
                                               const float* __restrict__ tarr,
                                               float* __restrict__ out)
{
    __shared__ float wred[4][6];
    __shared__ float sc;
    const int tid = threadIdx.x, lane = tid & 63, wv = tid >> 6;
    float pq = 0, pe = 0, pqq = 0, pqt = 0, ps = 0, pt = 0;
    for (int i = tid; i < NA; i += NT) {
        float q = rawq[i], s = sarr[i], t = tarr[i];
        pq += q; pe += esr[i]; pqq += q * s; pqt += q * t; ps += s; pt += t;
    }
    pq  = wave_reduce(pq);  pe = wave_reduce(pe);  pqq = wave_reduce(pqq);
    pqt = wave_reduce(pqt); ps = wave_reduce(ps);  pt  = wave_reduce(pt);
    if (lane == 0) {
        wred[wv][0] = pq; wred[wv][1] = pe; wred[wv][2] = pqq;
        wred[wv][3] = pqt; wred[wv][4] = ps; wred[wv][5] = pt;
    }
    __syncthreads();
    if (tid == 0) {
        float q  = wred[0][0] + wred[1][0] + wred[2][0] + wred[3][0];
        float e  = wred[0][1] + wred[1][1] + wred[2][1] + wred[3][1];
        float qq = wred[0][2] + wred[1][2] + wred[2][2] + wred[3][2];
        float qt = wred[0][3] + wred[1][3] + wred[2][3] + wred[3][3];
        float ss = wred[0][4] + wred[1][4] + wred[2][4] + wred[3][4];
        float tt = wred[0][5] + wred[1][5] + wred[2][5] + wred[3][5];
        float c = -q * (1.0f / (float)NA);
        sc = c;
        out[0] = 0.5f * (qq + c * (qt + ss) + c * c * tt) + e;
    }
    __syncthreads();
    const float c = sc;
    for (int i = tid; i < NA; i += NT) out[1 + i] = rawq[i] + c;
}

extern "C" void kernel_launch(void* const* d_in, const int* in_sizes, int n_in,
                              void* d_out, int out_size, void* d_ws, size_t ws_size,
                              hipStream_t stream) {
    const float* pos = (const float*)d_in[0];
    const float* cw1 = (const float*)d_in[1];
    const float* cb1 = (const float*)d_in[2];
    const float* cw2 = (const float*)d_in[3];
    const float* cb2 = (const float*)d_in[4];
    const float* cw3 = (const float*)d_in[5];
    const float* cb3 = (const float*)d_in[6];
    const float* ew1 = (const float*)d_in[7];
    const float* eb1 = (const float*)d_in[8];
    const float* ew2 = (const float*)d_in[9];
    const float* eb2 = (const float*)d_in[10];
    const float* ew3 = (const float*)d_in[11];
    const float* eb3 = (const float*)d_in[12];
    float* out = (float*)d_out;

    float4* pxyzq = (float4*)d_ws;                  // 2048 float4
    float*  rawq  = (float*)(pxyzq + NA);           // 2048
    float*  esr   = rawq + NA;                      // 2048
    float*  sarr  = esr + NA;                       // 2048
    float*  tarr  = sarr + NA;                      // 2048

    k1_feat_mlp<<<NA / 4, NT, 0, stream>>>(pos,
                                           cw1, cb1, cw2, cb2, cw3, cb3,
                                           ew1, eb1, ew2, eb2, ew3, eb3,
                                           pxyzq, rawq, esr);
    k2_pair<<<NA, NT, 0, stream>>>(pxyzq, sarr, tarr);
    k3_final<<<1, NT, 0, stream>>>(rawq, esr, sarr, tarr, out);
}